// Round 4
// baseline (438.647 us; speedup 1.0000x reference)
//
#include <hip/hip_runtime.h>

#define N_NODES 50000
#define N_EDGES 800000
#define NB_SCAN 196  // ceil(N_NODES / 256)

typedef __attribute__((ext_vector_type(8))) short short8;
typedef __attribute__((ext_vector_type(4))) float f32x4;

__device__ __forceinline__ unsigned short f2bf(float f) {
  unsigned u = __float_as_uint(f);
  unsigned r = u + 0x7FFFu + ((u >> 16) & 1u);  // RNE
  return (unsigned short)(r >> 16);
}
__device__ __forceinline__ float bf2f(unsigned short h) {
  return __uint_as_float(((unsigned)h) << 16);
}

// ---------------- CSR build ----------------

__global__ __launch_bounds__(256) void count_deg_k(const int* __restrict__ dst,
                                                   int* __restrict__ deg) {
  int e = blockIdx.x * 256 + threadIdx.x;
  if (e < N_EDGES) atomicAdd(&deg[dst[e]], 1);
}

__global__ __launch_bounds__(256) void block_sum_k(const int* __restrict__ deg,
                                                   int* __restrict__ bsum) {
  int i = blockIdx.x * 256 + threadIdx.x;
  int v = (i < N_NODES) ? deg[i] : 0;
#pragma unroll
  for (int o = 32; o > 0; o >>= 1) v += __shfl_down(v, o, 64);
  __shared__ int s[4];
  if ((threadIdx.x & 63) == 0) s[threadIdx.x >> 6] = v;
  __syncthreads();
  if (threadIdx.x == 0) bsum[blockIdx.x] = s[0] + s[1] + s[2] + s[3];
}

__global__ __launch_bounds__(256) void scan_bsum_k(const int* __restrict__ bsum,
                                                   int* __restrict__ boffs) {
  __shared__ int sh[256];
  int t = threadIdx.x;
  sh[t] = (t < NB_SCAN) ? bsum[t] : 0;
  __syncthreads();
  for (int o = 1; o < 256; o <<= 1) {
    int v = (t >= o) ? sh[t - o] : 0;
    __syncthreads();
    sh[t] += v;
    __syncthreads();
  }
  if (t < NB_SCAN) boffs[t] = (t == 0) ? 0 : sh[t - 1];
}

__global__ __launch_bounds__(256) void apply_scan_k(const int* __restrict__ deg,
                                                    const int* __restrict__ boffs,
                                                    int* __restrict__ offs,
                                                    int* __restrict__ cur) {
  __shared__ int sh[256];
  int t = threadIdx.x;
  int i = blockIdx.x * 256 + t;
  int v = (i < N_NODES) ? deg[i] : 0;
  sh[t] = v;
  __syncthreads();
  for (int o = 1; o < 256; o <<= 1) {
    int w = (t >= o) ? sh[t - o] : 0;
    __syncthreads();
    sh[t] += w;
    __syncthreads();
  }
  int excl = boffs[blockIdx.x] + ((t == 0) ? 0 : sh[t - 1]);
  if (i < N_NODES) {
    offs[i] = excl;
    cur[i] = excl;
  }
}

__global__ __launch_bounds__(256) void fill_csr_k(const int* __restrict__ src,
                                                  const int* __restrict__ dst,
                                                  int* __restrict__ cur,
                                                  int* __restrict__ csr) {
  int e = blockIdx.x * 256 + threadIdx.x;
  if (e < N_EDGES) {
    int p = atomicAdd(&cur[dst[e]], 1);
    csr[p] = src[e];
  }
}

// ---------------- mean aggregation: D/4 lanes per node, float4 gathers ----------------

template <int D, bool FUSE>
__global__ __launch_bounds__(256) void agg_mean_k(const float* __restrict__ in,
                                                  float* __restrict__ out,
                                                  const int* __restrict__ offs,
                                                  const int* __restrict__ deg,
                                                  const int* __restrict__ csr,
                                                  const float* __restrict__ bias,
                                                  const float* __restrict__ addend) {
  constexpr int L = D / 4;
  constexpr int NPB = 256 / L;
  int node = blockIdx.x * NPB + threadIdx.x / L;
  int lane = threadIdx.x & (L - 1);
  if (node >= N_NODES) return;
  int start = offs[node];
  int d = deg[node];
  float4 acc = make_float4(0.f, 0.f, 0.f, 0.f);
  int e = 0;
  for (; e + 1 < d; e += 2) {
    int s0 = csr[start + e];
    int s1 = csr[start + e + 1];
    float4 v0 = *(const float4*)(in + (size_t)s0 * D + lane * 4);
    float4 v1 = *(const float4*)(in + (size_t)s1 * D + lane * 4);
    acc.x += v0.x + v1.x;
    acc.y += v0.y + v1.y;
    acc.z += v0.z + v1.z;
    acc.w += v0.w + v1.w;
  }
  if (e < d) {
    int s0 = csr[start + e];
    float4 v0 = *(const float4*)(in + (size_t)s0 * D + lane * 4);
    acc.x += v0.x;
    acc.y += v0.y;
    acc.z += v0.z;
    acc.w += v0.w;
  }
  float inv = d > 0 ? 1.0f / (float)d : 0.0f;
  float4 o;
  o.x = acc.x * inv;
  o.y = acc.y * inv;
  o.z = acc.z * inv;
  o.w = acc.w * inv;
  if constexpr (FUSE) {
    float4 bv = *(const float4*)(bias + lane * 4);
    float4 av = *(const float4*)(addend + (size_t)node * D + lane * 4);
    o.x += bv.x + av.x;
    o.y += bv.y + av.y;
    o.z += bv.z + av.z;
    o.w += bv.w + av.w;
  }
  *(float4*)(out + (size_t)node * D + lane * 4) = o;
}

// ---------------- W prep: fp32 -> bf16 hi/lo split ----------------

__global__ __launch_bounds__(256) void wprep_k(
    const float* __restrict__ Wl1, const float* __restrict__ Wr1,
    const float* __restrict__ Wl2, const float* __restrict__ Wr2,
    const float* __restrict__ Wl3, const float* __restrict__ Wr3,
    unsigned short* h_l1, unsigned short* l_l1,
    unsigned short* h_r1, unsigned short* l_r1,
    unsigned short* h_c2, unsigned short* l_c2,
    unsigned short* h_l3, unsigned short* l_l3,
    unsigned short* h_r3, unsigned short* l_r3) {
  int i = blockIdx.x * 256 + threadIdx.x;  // 0..65535
  const float* s;
  unsigned short *ph, *pl;
  int j;
  if (i < 16384) { s = Wl1; ph = h_l1; pl = l_l1; j = i; }
  else if (i < 32768) { s = Wr1; ph = h_r1; pl = l_r1; j = i - 16384; }
  else if (i < 40960) { s = Wl2; ph = h_c2; pl = l_c2; j = i - 32768; }
  else if (i < 49152) { s = Wr2; ph = h_c2 + 8192; pl = l_c2 + 8192; j = i - 40960; }
  else if (i < 57344) { s = Wl3; ph = h_l3; pl = l_l3; j = i - 49152; }
  else { s = Wr3; ph = h_r3; pl = l_r3; j = i - 57344; }
  float v = s[j];
  unsigned short hb = f2bf(v);
  ph[j] = hb;
  pl[j] = f2bf(v - bf2f(hb));
}

// ---------------- split-bf16 MFMA GEMM ----------------
// C[M x 128] = A1@W1^T (+ A2@W2^T) (+bias), W as precomputed bf16 hi/lo [128 x K].
// fp32 emulated as hi+lo bf16: A.B ~= Ah.Bh + Ah.Bl + Al.Bh (3 MFMAs, err ~2^-16).
// Each wave owns 16 rows x 128 cols (8 16x16 tiles) -> A rows read exactly once,
// no LDS, no barriers. W fragments read from global (L1-resident, ~64KB).
// SPLIT: cols 0-63 -> C, 64-127 -> C2 (layer-2 dual-output, no bias).

template <int K, bool DUAL, bool SPLIT>
__global__ __launch_bounds__(256) void gemm_mfma_k(
    const float* __restrict__ A1, const unsigned short* __restrict__ W1h,
    const unsigned short* __restrict__ W1l,
    const float* __restrict__ A2, const unsigned short* __restrict__ W2h,
    const unsigned short* __restrict__ W2l,
    const float* __restrict__ bias, float* __restrict__ C,
    float* __restrict__ C2, int M) {
  int wave = threadIdx.x >> 6;
  int lane = threadIdx.x & 63;
  int l15 = lane & 15;
  int lq = lane >> 4;  // quad 0..3
  int row0 = blockIdx.x * 64 + wave * 16;
  int arow = row0 + l15;
  if (arow >= M) arow = M - 1;  // clamp; corrupted rows are store-guarded
  f32x4 acc[8];
#pragma unroll
  for (int c = 0; c < 8; ++c) acc[c] = (f32x4){0.f, 0.f, 0.f, 0.f};

  constexpr int NOP = DUAL ? 2 : 1;
#pragma unroll
  for (int op = 0; op < NOP; ++op) {
    const float* A = op ? A2 : A1;
    const unsigned short* Wh = op ? W2h : W1h;
    const unsigned short* Wl = op ? W2l : W1l;
    const float* abase = A + (size_t)arow * K;
#pragma unroll
    for (int k0 = 0; k0 < K; k0 += 32) {
      int kf = k0 + lq * 8;  // A[m=l15][k=lq*8+j] fragment layout
      f32x4 a0 = *(const f32x4*)(abase + kf);
      f32x4 a1 = *(const f32x4*)(abase + kf + 4);
      short8 ah, al;
#pragma unroll
      for (int j = 0; j < 4; ++j) {
        float v = a0[j];
        unsigned short hb = f2bf(v);
        ah[j] = (short)hb;
        al[j] = (short)f2bf(v - bf2f(hb));
      }
#pragma unroll
      for (int j = 0; j < 4; ++j) {
        float v = a1[j];
        unsigned short hb = f2bf(v);
        ah[4 + j] = (short)hb;
        al[4 + j] = (short)f2bf(v - bf2f(hb));
      }
#pragma unroll
      for (int ct = 0; ct < 8; ++ct) {
        // B[k=lq*8+j][n=ct*16+l15] = W[n][k]
        size_t wi = (size_t)(ct * 16 + l15) * K + kf;
        short8 bh = *(const short8*)(Wh + wi);
        short8 bl = *(const short8*)(Wl + wi);
        acc[ct] = __builtin_amdgcn_mfma_f32_16x16x32_bf16(ah, bh, acc[ct], 0, 0, 0);
        acc[ct] = __builtin_amdgcn_mfma_f32_16x16x32_bf16(ah, bl, acc[ct], 0, 0, 0);
        acc[ct] = __builtin_amdgcn_mfma_f32_16x16x32_bf16(al, bh, acc[ct], 0, 0, 0);
      }
    }
  }
  // epilogue: C/D layout col=lane&15, row=(lane>>4)*4+reg
#pragma unroll
  for (int r = 0; r < 4; ++r) {
    int row = row0 + lq * 4 + r;
    if (row >= M) continue;
#pragma unroll
    for (int ct = 0; ct < 8; ++ct) {
      int col = ct * 16 + l15;
      float v = acc[ct][r];
      if constexpr (SPLIT) {
        if (col < 64)
          C[(size_t)row * 64 + col] = v;
        else
          C2[(size_t)row * 64 + (col - 64)] = v;
      } else {
        v += bias[col];
        C[(size_t)row * 128 + col] = v;
      }
    }
  }
}

extern "C" void kernel_launch(void* const* d_in, const int* in_sizes, int n_in,
                              void* d_out, int out_size, void* d_ws, size_t ws_size,
                              hipStream_t stream) {
  const float* x   = (const float*)d_in[0];
  const int* ei    = (const int*)d_in[1];
  const float* Wl1 = (const float*)d_in[2];
  const float* b1  = (const float*)d_in[3];
  const float* Wr1 = (const float*)d_in[4];
  const float* Wl2 = (const float*)d_in[5];
  const float* b2  = (const float*)d_in[6];
  const float* Wr2 = (const float*)d_in[7];
  const float* Wl3 = (const float*)d_in[8];
  const float* b3  = (const float*)d_in[9];
  const float* Wr3 = (const float*)d_in[10];
  float* out = (float*)d_out;

  const int* src = ei;            // edge_index[0]
  const int* dst = ei + N_EDGES;  // edge_index[1]

  char* ws = (char*)d_ws;
  size_t off = 0;
  auto take = [&](size_t bytes) {
    void* p = ws + off;
    off += (bytes + 255) & ~(size_t)255;
    return p;
  };
  int* deg   = (int*)take((size_t)N_NODES * 4);
  int* offs  = (int*)take((size_t)N_NODES * 4);
  int* cur   = (int*)take((size_t)N_NODES * 4);
  int* csr   = (int*)take((size_t)N_EDGES * 4);
  int* bsum  = (int*)take((size_t)NB_SCAN * 4);
  int* boffs = (int*)take((size_t)NB_SCAN * 4);
  float* A   = (float*)take((size_t)N_NODES * 128 * 4);  // agg buffer (m1, m3)
  float* Cb  = (float*)take((size_t)N_NODES * 128 * 4);  // h1, then h2 (Nx64)
  float* P   = (float*)take((size_t)N_NODES * 64 * 4);   // p2 = h1 @ Wl2^T
  float* R   = (float*)take((size_t)N_NODES * 64 * 4);   // r2 = h1 @ Wr2^T
  // bf16 hi/lo weight buffers
  unsigned short* h_l1 = (unsigned short*)take(16384 * 2);
  unsigned short* l_l1 = (unsigned short*)take(16384 * 2);
  unsigned short* h_r1 = (unsigned short*)take(16384 * 2);
  unsigned short* l_r1 = (unsigned short*)take(16384 * 2);
  unsigned short* h_c2 = (unsigned short*)take(16384 * 2);
  unsigned short* l_c2 = (unsigned short*)take(16384 * 2);
  unsigned short* h_l3 = (unsigned short*)take(8192 * 2);
  unsigned short* l_l3 = (unsigned short*)take(8192 * 2);
  unsigned short* h_r3 = (unsigned short*)take(8192 * 2);
  unsigned short* l_r3 = (unsigned short*)take(8192 * 2);

  const int eb = (N_EDGES + 255) / 256;  // 3125
  const int gg = (N_NODES + 63) / 64;    // 782

  // weight split (independent of CSR chain)
  wprep_k<<<256, 256, 0, stream>>>(Wl1, Wr1, Wl2, Wr2, Wl3, Wr3, h_l1, l_l1, h_r1,
                                   l_r1, h_c2, l_c2, h_l3, l_l3, h_r3, l_r3);

  // CSR build (parallel scan)
  hipMemsetAsync(deg, 0, (size_t)N_NODES * 4, stream);
  count_deg_k<<<eb, 256, 0, stream>>>(dst, deg);
  block_sum_k<<<NB_SCAN, 256, 0, stream>>>(deg, bsum);
  scan_bsum_k<<<1, 256, 0, stream>>>(bsum, boffs);
  apply_scan_k<<<NB_SCAN, 256, 0, stream>>>(deg, boffs, offs, cur);
  fill_csr_k<<<eb, 256, 0, stream>>>(src, dst, cur, csr);

  // layer 1: m1 = mean(x); h1 = m1@Wl1^T + x@Wr1^T + b1
  agg_mean_k<128, false><<<6250, 256, 0, stream>>>(x, A, offs, deg, csr, nullptr, nullptr);
  gemm_mfma_k<128, true, false><<<gg, 256, 0, stream>>>(A, h_l1, l_l1, x, h_r1, l_r1,
                                                        b1, Cb, nullptr, N_NODES);

  // layer 2 (project-then-aggregate): p2 = h1@Wl2^T, r2 = h1@Wr2^T; h2 = mean(p2)+b2+r2
  gemm_mfma_k<128, false, true><<<gg, 256, 0, stream>>>(Cb, h_c2, l_c2, nullptr, nullptr,
                                                        nullptr, nullptr, P, R, N_NODES);
  agg_mean_k<64, true><<<3125, 256, 0, stream>>>(P, Cb, offs, deg, csr, b2, R);  // h2 in Cb

  // layer 3 (aggregate-then-project): m3 = mean(h2); out = m3@Wl3^T + h2@Wr3^T + b3
  agg_mean_k<64, false><<<3125, 256, 0, stream>>>(Cb, A, offs, deg, csr, nullptr, nullptr);
  gemm_mfma_k<64, true, false><<<gg, 256, 0, stream>>>(A, h_l3, l_l3, Cb, h_r3, l_r3,
                                                       b3, out, nullptr, N_NODES);
}

// Round 5
// 321.740 us; speedup vs baseline: 1.3634x; 1.3634x over previous
//
#include <hip/hip_runtime.h>

#define N_NODES 50000
#define N_EDGES 800000
#define NB_SCAN 196  // ceil(N_NODES / 256)

typedef __attribute__((ext_vector_type(8))) _Float16 half8;
typedef __attribute__((ext_vector_type(4))) float f32x4;

// ---------------- CSR build ----------------

__global__ __launch_bounds__(256) void count_deg_k(const int* __restrict__ dst,
                                                   int* __restrict__ deg) {
  int e = blockIdx.x * 256 + threadIdx.x;
  if (e < N_EDGES) atomicAdd(&deg[dst[e]], 1);
}

__global__ __launch_bounds__(256) void block_sum_k(const int* __restrict__ deg,
                                                   int* __restrict__ bsum) {
  int i = blockIdx.x * 256 + threadIdx.x;
  int v = (i < N_NODES) ? deg[i] : 0;
#pragma unroll
  for (int o = 32; o > 0; o >>= 1) v += __shfl_down(v, o, 64);
  __shared__ int s[4];
  if ((threadIdx.x & 63) == 0) s[threadIdx.x >> 6] = v;
  __syncthreads();
  if (threadIdx.x == 0) bsum[blockIdx.x] = s[0] + s[1] + s[2] + s[3];
}

__global__ __launch_bounds__(256) void scan_bsum_k(const int* __restrict__ bsum,
                                                   int* __restrict__ boffs) {
  __shared__ int sh[256];
  int t = threadIdx.x;
  sh[t] = (t < NB_SCAN) ? bsum[t] : 0;
  __syncthreads();
  for (int o = 1; o < 256; o <<= 1) {
    int v = (t >= o) ? sh[t - o] : 0;
    __syncthreads();
    sh[t] += v;
    __syncthreads();
  }
  if (t < NB_SCAN) boffs[t] = (t == 0) ? 0 : sh[t - 1];
}

__global__ __launch_bounds__(256) void apply_scan_k(const int* __restrict__ deg,
                                                    const int* __restrict__ boffs,
                                                    int* __restrict__ offs,
                                                    int* __restrict__ cur) {
  __shared__ int sh[256];
  int t = threadIdx.x;
  int i = blockIdx.x * 256 + t;
  int v = (i < N_NODES) ? deg[i] : 0;
  sh[t] = v;
  __syncthreads();
  for (int o = 1; o < 256; o <<= 1) {
    int w = (t >= o) ? sh[t - o] : 0;
    __syncthreads();
    sh[t] += w;
    __syncthreads();
  }
  int excl = boffs[blockIdx.x] + ((t == 0) ? 0 : sh[t - 1]);
  if (i < N_NODES) {
    offs[i] = excl;
    cur[i] = excl;
  }
}

__global__ __launch_bounds__(256) void fill_csr_k(const int* __restrict__ src,
                                                  const int* __restrict__ dst,
                                                  int* __restrict__ cur,
                                                  int* __restrict__ csr) {
  int e = blockIdx.x * 256 + threadIdx.x;
  if (e < N_EDGES) {
    int p = atomicAdd(&cur[dst[e]], 1);
    csr[p] = src[e];
  }
}

// ---------------- x -> fp16 cast ----------------

__global__ __launch_bounds__(256) void xcast_k(const float* __restrict__ x,
                                               _Float16* __restrict__ xh) {
  int i = blockIdx.x * 256 + threadIdx.x;  // half8 group index
  if (i >= N_NODES * 16) return;           // 128/8 = 16 groups per node
  const float4* xp = (const float4*)x;
  float4 a = xp[2 * i];
  float4 b = xp[2 * i + 1];
  half8 h;
  h[0] = (_Float16)a.x; h[1] = (_Float16)a.y; h[2] = (_Float16)a.z; h[3] = (_Float16)a.w;
  h[4] = (_Float16)b.x; h[5] = (_Float16)b.y; h[6] = (_Float16)b.z; h[7] = (_Float16)b.w;
  ((half8*)xh)[i] = h;
}

// ---------------- W prep: fp32 -> fp16 hi/lo, packed B-fragment layout ----------------
// Packed layout (NN=128 rows per logical W): ph[((kb*128 + n)*4 + lq)*8 + j] =
// W[n][kb*32 + lq*8 + j]. A wave's fragment load (n = n0+l15, offset (l15*4+lq)*8)
// then covers one contiguous 1KB chunk -> perfectly coalesced.

__global__ __launch_bounds__(256) void wprep_k(
    const float* __restrict__ Wl1, const float* __restrict__ Wr1,
    const float* __restrict__ Wl2, const float* __restrict__ Wr2,
    const float* __restrict__ Wl3, const float* __restrict__ Wr3,
    _Float16* ph_l1, _Float16* pl_l1, _Float16* ph_r1, _Float16* pl_r1,
    _Float16* ph_c2, _Float16* pl_c2, _Float16* ph_l3, _Float16* pl_l3,
    _Float16* ph_r3, _Float16* pl_r3) {
  int t = blockIdx.x * 256 + threadIdx.x;  // fragment index, 8192 total
  if (t >= 8192) return;
  const float *S0, *S1 = nullptr;
  _Float16 *ph, *pl;
  int f, K;
  if (t < 2048)      { f = t;        ph = ph_l1; pl = pl_l1; S0 = Wl1; K = 128; }
  else if (t < 4096) { f = t - 2048; ph = ph_r1; pl = pl_r1; S0 = Wr1; K = 128; }
  else if (t < 6144) { f = t - 4096; ph = ph_c2; pl = pl_c2; S0 = Wl2; S1 = Wr2; K = 128; }
  else if (t < 7168) { f = t - 6144; ph = ph_l3; pl = pl_l3; S0 = Wl3; K = 64; }
  else               { f = t - 7168; ph = ph_r3; pl = pl_r3; S0 = Wr3; K = 64; }
  int kb = f >> 9;        // f / (128*4)
  int rem = f & 511;
  int n = rem >> 2;
  int lq = rem & 3;
  const float* srow = (S1 && n >= 64) ? (S1 + (size_t)(n - 64) * K) : (S0 + (size_t)n * K);
  int kbase = kb * 32 + lq * 8;
#pragma unroll
  for (int j = 0; j < 8; ++j) {
    float v = srow[kbase + j];
    _Float16 hi = (_Float16)v;
    ph[f * 8 + j] = hi;
    pl[f * 8 + j] = (_Float16)(v - (float)hi);
  }
}

// ---------------- fp16 mean aggregation: D/8 lanes/node, 16B gathers, 4-unroll ----------------

template <int D, bool FUSE>
__global__ __launch_bounds__(256) void agg_f16_k(const _Float16* __restrict__ in,
                                                 _Float16* __restrict__ out,
                                                 const int* __restrict__ offs,
                                                 const int* __restrict__ deg,
                                                 const int* __restrict__ csr,
                                                 const float* __restrict__ bias,
                                                 const _Float16* __restrict__ addend) {
  constexpr int L = D / 8;       // lanes per node (16 for D=128, 8 for D=64)
  constexpr int NPB = 256 / L;   // nodes per block
  int node = blockIdx.x * NPB + threadIdx.x / L;
  int lane = threadIdx.x & (L - 1);
  if (node >= N_NODES) return;
  int start = offs[node];
  int d = deg[node];
  const half8* ip = (const half8*)in;
  float acc[8];
#pragma unroll
  for (int j = 0; j < 8; ++j) acc[j] = 0.f;
  int e = 0;
  for (; e + 3 < d; e += 4) {
    int s0 = csr[start + e];
    int s1 = csr[start + e + 1];
    int s2 = csr[start + e + 2];
    int s3 = csr[start + e + 3];
    half8 v0 = ip[(size_t)s0 * L + lane];
    half8 v1 = ip[(size_t)s1 * L + lane];
    half8 v2 = ip[(size_t)s2 * L + lane];
    half8 v3 = ip[(size_t)s3 * L + lane];
#pragma unroll
    for (int j = 0; j < 8; ++j)
      acc[j] += ((float)v0[j] + (float)v1[j]) + ((float)v2[j] + (float)v3[j]);
  }
  for (; e < d; ++e) {
    int s0 = csr[start + e];
    half8 v0 = ip[(size_t)s0 * L + lane];
#pragma unroll
    for (int j = 0; j < 8; ++j) acc[j] += (float)v0[j];
  }
  float inv = d > 0 ? 1.0f / (float)d : 0.0f;
  half8 o;
  if constexpr (FUSE) {
    half8 av = ((const half8*)addend)[(size_t)node * L + lane];
#pragma unroll
    for (int j = 0; j < 8; ++j)
      o[j] = (_Float16)(acc[j] * inv + bias[lane * 8 + j] + (float)av[j]);
  } else {
#pragma unroll
    for (int j = 0; j < 8; ++j) o[j] = (_Float16)(acc[j] * inv);
  }
  ((half8*)out)[(size_t)node * L + lane] = o;
}

// ---------------- fp16 MFMA GEMM, packed W ----------------
// Wave: 16 rows x 64 cols (4 tiles), 2 col-groups per row-block -> grid 1564.
// W split hi/lo fp16 (exact-ish): A.W ~= A.Wh + A.Wl, 2 MFMAs per tile per k-step.
// A-fragment layout A[m=lane&15][k=(lane>>4)*8+j]; C/D col=lane&15, row=(lane>>4)*4+r.

template <int K, bool DUAL, bool SPLIT, bool OUT32>
__global__ __launch_bounds__(256, 2) void gemm_f16_k(
    const _Float16* __restrict__ A1, const _Float16* __restrict__ W1h,
    const _Float16* __restrict__ W1l,
    const _Float16* __restrict__ A2, const _Float16* __restrict__ W2h,
    const _Float16* __restrict__ W2l,
    const float* __restrict__ bias, _Float16* __restrict__ C16,
    float* __restrict__ C32, _Float16* __restrict__ O2) {
  int wave = threadIdx.x >> 6;
  int lane = threadIdx.x & 63;
  int l15 = lane & 15;
  int lq = lane >> 4;
  int rowblk = blockIdx.x >> 1;
  int colg = blockIdx.x & 1;
  int rg = rowblk * 4 + wave;
  if (rg >= N_NODES / 16) return;  // 3125, exact
  int row0 = rg << 4;
  constexpr int KB = K / 32;
  constexpr int NN = 128;
  const int woff = (l15 * 4 + lq) * 8;
  f32x4 acc[4];
#pragma unroll
  for (int c = 0; c < 4; ++c) acc[c] = (f32x4){0.f, 0.f, 0.f, 0.f};

  constexpr int NOP = DUAL ? 2 : 1;
#pragma unroll
  for (int op = 0; op < NOP; ++op) {
    const _Float16* A = op ? A2 : A1;
    const _Float16* Wh = op ? W2h : W1h;
    const _Float16* Wl = op ? W2l : W1l;
    const _Float16* ab = A + (size_t)(row0 + l15) * K + lq * 8;
    half8 af[KB];
#pragma unroll
    for (int kb = 0; kb < KB; ++kb) af[kb] = *(const half8*)(ab + kb * 32);
#pragma unroll
    for (int kb = 0; kb < KB; ++kb) {
#pragma unroll
      for (int ct = 0; ct < 4; ++ct) {
        int n0 = colg * 64 + ct * 16;
        size_t base = (size_t)(kb * NN + n0) * 32 + woff;
        half8 bh = *(const half8*)(Wh + base);
        half8 bl = *(const half8*)(Wl + base);
        acc[ct] = __builtin_amdgcn_mfma_f32_16x16x32_f16(af[kb], bh, acc[ct], 0, 0, 0);
        acc[ct] = __builtin_amdgcn_mfma_f32_16x16x32_f16(af[kb], bl, acc[ct], 0, 0, 0);
      }
    }
  }
  // epilogue
#pragma unroll
  for (int r = 0; r < 4; ++r) {
    int row = row0 + lq * 4 + r;
#pragma unroll
    for (int ct = 0; ct < 4; ++ct) {
      int col = colg * 64 + ct * 16 + l15;
      float v = acc[ct][r];
      if constexpr (SPLIT) {
        if (col < 64)
          C16[(size_t)row * 64 + col] = (_Float16)v;
        else
          O2[(size_t)row * 64 + (col - 64)] = (_Float16)v;
      } else {
        v += bias[col];
        if constexpr (OUT32)
          C32[(size_t)row * 128 + col] = v;
        else
          C16[(size_t)row * 128 + col] = (_Float16)v;
      }
    }
  }
}

extern "C" void kernel_launch(void* const* d_in, const int* in_sizes, int n_in,
                              void* d_out, int out_size, void* d_ws, size_t ws_size,
                              hipStream_t stream) {
  const float* x   = (const float*)d_in[0];
  const int* ei    = (const int*)d_in[1];
  const float* Wl1 = (const float*)d_in[2];
  const float* b1  = (const float*)d_in[3];
  const float* Wr1 = (const float*)d_in[4];
  const float* Wl2 = (const float*)d_in[5];
  const float* b2  = (const float*)d_in[6];
  const float* Wr2 = (const float*)d_in[7];
  const float* Wl3 = (const float*)d_in[8];
  const float* b3  = (const float*)d_in[9];
  const float* Wr3 = (const float*)d_in[10];
  float* out = (float*)d_out;

  const int* src = ei;            // edge_index[0]
  const int* dst = ei + N_EDGES;  // edge_index[1]

  char* ws = (char*)d_ws;
  size_t off = 0;
  auto take = [&](size_t bytes) {
    void* p = ws + off;
    off += (bytes + 255) & ~(size_t)255;
    return p;
  };
  int* deg   = (int*)take((size_t)N_NODES * 4);
  int* offs  = (int*)take((size_t)N_NODES * 4);
  int* cur   = (int*)take((size_t)N_NODES * 4);
  int* csr   = (int*)take((size_t)N_EDGES * 4);
  int* bsum  = (int*)take((size_t)NB_SCAN * 4);
  int* boffs = (int*)take((size_t)NB_SCAN * 4);
  _Float16* xh  = (_Float16*)take((size_t)N_NODES * 128 * 2);
  _Float16* m1h = (_Float16*)take((size_t)N_NODES * 128 * 2);
  _Float16* h1h = (_Float16*)take((size_t)N_NODES * 128 * 2);
  _Float16* Ph  = (_Float16*)take((size_t)N_NODES * 64 * 2);
  _Float16* Rh  = (_Float16*)take((size_t)N_NODES * 64 * 2);
  _Float16* h2h = (_Float16*)take((size_t)N_NODES * 64 * 2);
  _Float16* m3h = (_Float16*)take((size_t)N_NODES * 64 * 2);
  _Float16* ph_l1 = (_Float16*)take(16384 * 2);
  _Float16* pl_l1 = (_Float16*)take(16384 * 2);
  _Float16* ph_r1 = (_Float16*)take(16384 * 2);
  _Float16* pl_r1 = (_Float16*)take(16384 * 2);
  _Float16* ph_c2 = (_Float16*)take(16384 * 2);
  _Float16* pl_c2 = (_Float16*)take(16384 * 2);
  _Float16* ph_l3 = (_Float16*)take(8192 * 2);
  _Float16* pl_l3 = (_Float16*)take(8192 * 2);
  _Float16* ph_r3 = (_Float16*)take(8192 * 2);
  _Float16* pl_r3 = (_Float16*)take(8192 * 2);

  const int eb = (N_EDGES + 255) / 256;  // 3125
  const int gg = 1564;                   // 782 row-blocks x 2 col-groups

  // prep (independent of CSR chain)
  xcast_k<<<3125, 256, 0, stream>>>(x, xh);
  wprep_k<<<32, 256, 0, stream>>>(Wl1, Wr1, Wl2, Wr2, Wl3, Wr3, ph_l1, pl_l1, ph_r1,
                                  pl_r1, ph_c2, pl_c2, ph_l3, pl_l3, ph_r3, pl_r3);

  // CSR build (parallel scan)
  hipMemsetAsync(deg, 0, (size_t)N_NODES * 4, stream);
  count_deg_k<<<eb, 256, 0, stream>>>(dst, deg);
  block_sum_k<<<NB_SCAN, 256, 0, stream>>>(deg, bsum);
  scan_bsum_k<<<1, 256, 0, stream>>>(bsum, boffs);
  apply_scan_k<<<NB_SCAN, 256, 0, stream>>>(deg, boffs, offs, cur);
  fill_csr_k<<<eb, 256, 0, stream>>>(src, dst, cur, csr);

  // layer 1: m1 = mean(x); h1 = m1@Wl1^T + x@Wr1^T + b1  (fp16 out)
  agg_f16_k<128, false><<<3125, 256, 0, stream>>>(xh, m1h, offs, deg, csr, nullptr, nullptr);
  gemm_f16_k<128, true, false, false><<<gg, 256, 0, stream>>>(
      m1h, ph_l1, pl_l1, xh, ph_r1, pl_r1, b1, h1h, nullptr, nullptr);

  // layer 2 (project-then-aggregate): [P|R] = h1 @ [Wl2;Wr2]^T; h2 = mean(P)+b2+R
  gemm_f16_k<128, false, true, false><<<gg, 256, 0, stream>>>(
      h1h, ph_c2, pl_c2, nullptr, nullptr, nullptr, nullptr, Ph, nullptr, Rh);
  agg_f16_k<64, true><<<1563, 256, 0, stream>>>(Ph, h2h, offs, deg, csr, b2, Rh);

  // layer 3 (aggregate-then-project): m3 = mean(h2); out = m3@Wl3^T + h2@Wr3^T + b3
  agg_f16_k<64, false><<<1563, 256, 0, stream>>>(h2h, m3h, offs, deg, csr, nullptr, nullptr);
  gemm_f16_k<64, true, false, true><<<gg, 256, 0, stream>>>(
      m3h, ph_l3, pl_l3, h2h, ph_r3, pl_r3, b3, nullptr, out, nullptr);
}

// Round 6
// 271.202 us; speedup vs baseline: 1.6174x; 1.1863x over previous
//
#include <hip/hip_runtime.h>

#define N_NODES 50000
#define N_EDGES 800000
#define BUCKETS 196   // ceil(N_NODES / 256)
#define ECHUNK 4096
#define EBLKS 196     // ceil(N_EDGES / ECHUNK)

typedef __attribute__((ext_vector_type(8))) _Float16 half8;
typedef __attribute__((ext_vector_type(4))) float f32x4;

// ---------------- binned CSR build ----------------
// Bucket b = dst >> 8 (256 consecutive dst nodes per bucket).
// Packed edge record: bits 0-15 = src (N_NODES < 65536), bits 16-23 = dst & 255.

__global__ __launch_bounds__(256) void binhist_k(const int* __restrict__ dst,
                                                 int* __restrict__ ghist) {
  __shared__ int h[BUCKETS];
  int t = threadIdx.x;
  for (int i = t; i < BUCKETS; i += 256) h[i] = 0;
  __syncthreads();
  int e0 = blockIdx.x * ECHUNK;
  int eend = e0 + ECHUNK < N_EDGES ? e0 + ECHUNK : N_EDGES;
  for (int e = e0 + t; e < eend; e += 256) atomicAdd(&h[dst[e] >> 8], 1);
  __syncthreads();
  for (int i = t; i < BUCKETS; i += 256)
    if (h[i]) atomicAdd(&ghist[i], h[i]);
}

__global__ __launch_bounds__(256) void binscan_k(const int* __restrict__ ghist,
                                                 int* __restrict__ gbase,
                                                 int* __restrict__ gcur) {
  __shared__ int sh[256];
  int t = threadIdx.x;
  sh[t] = (t < BUCKETS) ? ghist[t] : 0;
  __syncthreads();
  for (int o = 1; o < 256; o <<= 1) {
    int v = (t >= o) ? sh[t - o] : 0;
    __syncthreads();
    sh[t] += v;
    __syncthreads();
  }
  if (t < BUCKETS) {
    int excl = (t == 0) ? 0 : sh[t - 1];
    gbase[t] = excl;
    gcur[t] = excl;
  }
}

__global__ __launch_bounds__(256) void binscatter_k(const int* __restrict__ src,
                                                    const int* __restrict__ dst,
                                                    int* __restrict__ gcur,
                                                    unsigned* __restrict__ binned) {
  __shared__ int h[BUCKETS];
  __shared__ int base[BUCKETS];
  int t = threadIdx.x;
  for (int i = t; i < BUCKETS; i += 256) h[i] = 0;
  __syncthreads();
  int e0 = blockIdx.x * ECHUNK;
  int eend = e0 + ECHUNK < N_EDGES ? e0 + ECHUNK : N_EDGES;
  for (int e = e0 + t; e < eend; e += 256) atomicAdd(&h[dst[e] >> 8], 1);
  __syncthreads();
  for (int i = t; i < BUCKETS; i += 256) {
    if (h[i]) base[i] = atomicAdd(&gcur[i], h[i]);
    h[i] = 0;  // reuse as local rank cursor
  }
  __syncthreads();
  for (int e = e0 + t; e < eend; e += 256) {
    int d = dst[e];
    int b = d >> 8;
    int r = atomicAdd(&h[b], 1);
    binned[base[b] + r] = (unsigned)src[e] | ((unsigned)(d & 255) << 16);
  }
}

// One block per bucket: derives per-node offs/deg (no separate count/scan pass)
// and groups edges node-contiguously into csr (ushort), all writes L2-local.
__global__ __launch_bounds__(256) void bucket_fill_k(const unsigned* __restrict__ binned,
                                                     const int* __restrict__ gbase,
                                                     const int* __restrict__ gend,
                                                     int* __restrict__ offs,
                                                     int* __restrict__ deg,
                                                     unsigned short* __restrict__ csr) {
  __shared__ int cnt[256];
  __shared__ int loc[256];
  __shared__ int cur[256];
  int b = blockIdx.x;
  int t = threadIdx.x;
  int base = gbase[b];
  int end = gend[b];
  cnt[t] = 0;
  __syncthreads();
  for (int e = base + t; e < end; e += 256) atomicAdd(&cnt[(binned[e] >> 16) & 255], 1);
  __syncthreads();
  loc[t] = cnt[t];
  __syncthreads();
  for (int o = 1; o < 256; o <<= 1) {
    int v = (t >= o) ? loc[t - o] : 0;
    __syncthreads();
    loc[t] += v;
    __syncthreads();
  }
  int excl = loc[t] - cnt[t];
  int node = b * 256 + t;
  if (node < N_NODES) {
    offs[node] = base + excl;
    deg[node] = cnt[t];
  }
  cur[t] = excl;
  __syncthreads();
  for (int e = base + t; e < end; e += 256) {
    unsigned r = binned[e];
    int dl = (r >> 16) & 255;
    int p = atomicAdd(&cur[dl], 1);
    csr[base + p] = (unsigned short)(r & 0xFFFF);
  }
}

// ---------------- x -> fp16 cast ----------------

__global__ __launch_bounds__(256) void xcast_k(const float* __restrict__ x,
                                               _Float16* __restrict__ xh) {
  int i = blockIdx.x * 256 + threadIdx.x;  // half8 group index
  if (i >= N_NODES * 16) return;
  const float4* xp = (const float4*)x;
  float4 a = xp[2 * i];
  float4 b = xp[2 * i + 1];
  half8 h;
  h[0] = (_Float16)a.x; h[1] = (_Float16)a.y; h[2] = (_Float16)a.z; h[3] = (_Float16)a.w;
  h[4] = (_Float16)b.x; h[5] = (_Float16)b.y; h[6] = (_Float16)b.z; h[7] = (_Float16)b.w;
  ((half8*)xh)[i] = h;
}

// ---------------- W prep: fp32 -> fp16 hi/lo, packed B-fragment layout ----------------
// ph[((kb*128 + n)*4 + lq)*8 + j] = W[n][kb*32 + lq*8 + j] -> wave fragment load is
// one contiguous 1KB chunk.

__global__ __launch_bounds__(256) void wprep_k(
    const float* __restrict__ Wl1, const float* __restrict__ Wr1,
    const float* __restrict__ Wl2, const float* __restrict__ Wr2,
    const float* __restrict__ Wl3, const float* __restrict__ Wr3,
    _Float16* ph_l1, _Float16* pl_l1, _Float16* ph_r1, _Float16* pl_r1,
    _Float16* ph_c2, _Float16* pl_c2, _Float16* ph_l3, _Float16* pl_l3,
    _Float16* ph_r3, _Float16* pl_r3) {
  int t = blockIdx.x * 256 + threadIdx.x;  // fragment index, 8192 total
  if (t >= 8192) return;
  const float *S0, *S1 = nullptr;
  _Float16 *ph, *pl;
  int f, K;
  if (t < 2048)      { f = t;        ph = ph_l1; pl = pl_l1; S0 = Wl1; K = 128; }
  else if (t < 4096) { f = t - 2048; ph = ph_r1; pl = pl_r1; S0 = Wr1; K = 128; }
  else if (t < 6144) { f = t - 4096; ph = ph_c2; pl = pl_c2; S0 = Wl2; S1 = Wr2; K = 128; }
  else if (t < 7168) { f = t - 6144; ph = ph_l3; pl = pl_l3; S0 = Wl3; K = 64; }
  else               { f = t - 7168; ph = ph_r3; pl = pl_r3; S0 = Wr3; K = 64; }
  int kb = f >> 9;
  int rem = f & 511;
  int n = rem >> 2;
  int lq = rem & 3;
  const float* srow = (S1 && n >= 64) ? (S1 + (size_t)(n - 64) * K) : (S0 + (size_t)n * K);
  int kbase = kb * 32 + lq * 8;
#pragma unroll
  for (int j = 0; j < 8; ++j) {
    float v = srow[kbase + j];
    _Float16 hi = (_Float16)v;
    ph[f * 8 + j] = hi;
    pl[f * 8 + j] = (_Float16)(v - (float)hi);
  }
}

// ---------------- fp16 mean aggregation: D/8 lanes/node, 16B gathers, 4-unroll ----------------

template <int D, bool FUSE>
__global__ __launch_bounds__(256) void agg_f16_k(const _Float16* __restrict__ in,
                                                 _Float16* __restrict__ out,
                                                 const int* __restrict__ offs,
                                                 const int* __restrict__ deg,
                                                 const unsigned short* __restrict__ csr,
                                                 const float* __restrict__ bias,
                                                 const _Float16* __restrict__ addend) {
  constexpr int L = D / 8;
  constexpr int NPB = 256 / L;
  int node = blockIdx.x * NPB + threadIdx.x / L;
  int lane = threadIdx.x & (L - 1);
  if (node >= N_NODES) return;
  int start = offs[node];
  int d = deg[node];
  const half8* ip = (const half8*)in;
  float acc[8];
#pragma unroll
  for (int j = 0; j < 8; ++j) acc[j] = 0.f;
  int e = 0;
  for (; e + 3 < d; e += 4) {
    int s0 = csr[start + e];
    int s1 = csr[start + e + 1];
    int s2 = csr[start + e + 2];
    int s3 = csr[start + e + 3];
    half8 v0 = ip[(size_t)s0 * L + lane];
    half8 v1 = ip[(size_t)s1 * L + lane];
    half8 v2 = ip[(size_t)s2 * L + lane];
    half8 v3 = ip[(size_t)s3 * L + lane];
#pragma unroll
    for (int j = 0; j < 8; ++j)
      acc[j] += ((float)v0[j] + (float)v1[j]) + ((float)v2[j] + (float)v3[j]);
  }
  for (; e < d; ++e) {
    int s0 = csr[start + e];
    half8 v0 = ip[(size_t)s0 * L + lane];
#pragma unroll
    for (int j = 0; j < 8; ++j) acc[j] += (float)v0[j];
  }
  float inv = d > 0 ? 1.0f / (float)d : 0.0f;
  half8 o;
  if constexpr (FUSE) {
    half8 av = ((const half8*)addend)[(size_t)node * L + lane];
#pragma unroll
    for (int j = 0; j < 8; ++j)
      o[j] = (_Float16)(acc[j] * inv + bias[lane * 8 + j] + (float)av[j]);
  } else {
#pragma unroll
    for (int j = 0; j < 8; ++j) o[j] = (_Float16)(acc[j] * inv);
  }
  ((half8*)out)[(size_t)node * L + lane] = o;
}

// ---------------- fp16 MFMA GEMM, packed W ----------------

template <int K, bool DUAL, bool SPLIT, bool OUT32>
__global__ __launch_bounds__(256, 2) void gemm_f16_k(
    const _Float16* __restrict__ A1, const _Float16* __restrict__ W1h,
    const _Float16* __restrict__ W1l,
    const _Float16* __restrict__ A2, const _Float16* __restrict__ W2h,
    const _Float16* __restrict__ W2l,
    const float* __restrict__ bias, _Float16* __restrict__ C16,
    float* __restrict__ C32, _Float16* __restrict__ O2) {
  int wave = threadIdx.x >> 6;
  int lane = threadIdx.x & 63;
  int l15 = lane & 15;
  int lq = lane >> 4;
  int rowblk = blockIdx.x >> 1;
  int colg = blockIdx.x & 1;
  int rg = rowblk * 4 + wave;
  if (rg >= N_NODES / 16) return;  // 3125, exact
  int row0 = rg << 4;
  constexpr int KB = K / 32;
  constexpr int NN = 128;
  const int woff = (l15 * 4 + lq) * 8;
  f32x4 acc[4];
#pragma unroll
  for (int c = 0; c < 4; ++c) acc[c] = (f32x4){0.f, 0.f, 0.f, 0.f};

  constexpr int NOP = DUAL ? 2 : 1;
#pragma unroll
  for (int op = 0; op < NOP; ++op) {
    const _Float16* A = op ? A2 : A1;
    const _Float16* Wh = op ? W2h : W1h;
    const _Float16* Wl = op ? W2l : W1l;
    const _Float16* ab = A + (size_t)(row0 + l15) * K + lq * 8;
    half8 af[KB];
#pragma unroll
    for (int kb = 0; kb < KB; ++kb) af[kb] = *(const half8*)(ab + kb * 32);
#pragma unroll
    for (int kb = 0; kb < KB; ++kb) {
#pragma unroll
      for (int ct = 0; ct < 4; ++ct) {
        int n0 = colg * 64 + ct * 16;
        size_t base = (size_t)(kb * NN + n0) * 32 + woff;
        half8 bh = *(const half8*)(Wh + base);
        half8 bl = *(const half8*)(Wl + base);
        acc[ct] = __builtin_amdgcn_mfma_f32_16x16x32_f16(af[kb], bh, acc[ct], 0, 0, 0);
        acc[ct] = __builtin_amdgcn_mfma_f32_16x16x32_f16(af[kb], bl, acc[ct], 0, 0, 0);
      }
    }
  }
#pragma unroll
  for (int r = 0; r < 4; ++r) {
    int row = row0 + lq * 4 + r;
#pragma unroll
    for (int ct = 0; ct < 4; ++ct) {
      int col = colg * 64 + ct * 16 + l15;
      float v = acc[ct][r];
      if constexpr (SPLIT) {
        if (col < 64)
          C16[(size_t)row * 64 + col] = (_Float16)v;
        else
          O2[(size_t)row * 64 + (col - 64)] = (_Float16)v;
      } else {
        v += bias[col];
        if constexpr (OUT32)
          C32[(size_t)row * 128 + col] = v;
        else
          C16[(size_t)row * 128 + col] = (_Float16)v;
      }
    }
  }
}

extern "C" void kernel_launch(void* const* d_in, const int* in_sizes, int n_in,
                              void* d_out, int out_size, void* d_ws, size_t ws_size,
                              hipStream_t stream) {
  const float* x   = (const float*)d_in[0];
  const int* ei    = (const int*)d_in[1];
  const float* Wl1 = (const float*)d_in[2];
  const float* b1  = (const float*)d_in[3];
  const float* Wr1 = (const float*)d_in[4];
  const float* Wl2 = (const float*)d_in[5];
  const float* b2  = (const float*)d_in[6];
  const float* Wr2 = (const float*)d_in[7];
  const float* Wl3 = (const float*)d_in[8];
  const float* b3  = (const float*)d_in[9];
  const float* Wr3 = (const float*)d_in[10];
  float* out = (float*)d_out;

  const int* src = ei;            // edge_index[0]
  const int* dst = ei + N_EDGES;  // edge_index[1]

  char* ws = (char*)d_ws;
  size_t off = 0;
  auto take = [&](size_t bytes) {
    void* p = ws + off;
    off += (bytes + 255) & ~(size_t)255;
    return p;
  };
  int* deg    = (int*)take((size_t)N_NODES * 4);
  int* offs   = (int*)take((size_t)N_NODES * 4);
  int* ghist  = (int*)take((size_t)BUCKETS * 4);
  int* gbase  = (int*)take((size_t)BUCKETS * 4);
  int* gcur   = (int*)take((size_t)BUCKETS * 4);
  unsigned* binned = (unsigned*)take((size_t)N_EDGES * 4);
  unsigned short* csr = (unsigned short*)take((size_t)N_EDGES * 2);
  _Float16* xh  = (_Float16*)take((size_t)N_NODES * 128 * 2);
  _Float16* m1h = (_Float16*)take((size_t)N_NODES * 128 * 2);
  _Float16* h1h = (_Float16*)take((size_t)N_NODES * 128 * 2);
  _Float16* Ph  = (_Float16*)take((size_t)N_NODES * 64 * 2);
  _Float16* Rh  = (_Float16*)take((size_t)N_NODES * 64 * 2);
  _Float16* h2h = (_Float16*)take((size_t)N_NODES * 64 * 2);
  _Float16* m3h = (_Float16*)take((size_t)N_NODES * 64 * 2);
  _Float16* ph_l1 = (_Float16*)take(16384 * 2);
  _Float16* pl_l1 = (_Float16*)take(16384 * 2);
  _Float16* ph_r1 = (_Float16*)take(16384 * 2);
  _Float16* pl_r1 = (_Float16*)take(16384 * 2);
  _Float16* ph_c2 = (_Float16*)take(16384 * 2);
  _Float16* pl_c2 = (_Float16*)take(16384 * 2);
  _Float16* ph_l3 = (_Float16*)take(8192 * 2);
  _Float16* pl_l3 = (_Float16*)take(8192 * 2);
  _Float16* ph_r3 = (_Float16*)take(8192 * 2);
  _Float16* pl_r3 = (_Float16*)take(8192 * 2);

  const int gg = 1564;  // 782 row-blocks x 2 col-groups

  // prep (independent of CSR chain)
  xcast_k<<<3125, 256, 0, stream>>>(x, xh);
  wprep_k<<<32, 256, 0, stream>>>(Wl1, Wr1, Wl2, Wr2, Wl3, Wr3, ph_l1, pl_l1, ph_r1,
                                  pl_r1, ph_c2, pl_c2, ph_l3, pl_l3, ph_r3, pl_r3);

  // binned CSR build
  hipMemsetAsync(ghist, 0, (size_t)BUCKETS * 4, stream);
  binhist_k<<<EBLKS, 256, 0, stream>>>(dst, ghist);
  binscan_k<<<1, 256, 0, stream>>>(ghist, gbase, gcur);
  binscatter_k<<<EBLKS, 256, 0, stream>>>(src, dst, gcur, binned);
  bucket_fill_k<<<BUCKETS, 256, 0, stream>>>(binned, gbase, gcur, offs, deg, csr);

  // layer 1: m1 = mean(x); h1 = m1@Wl1^T + x@Wr1^T + b1  (fp16 out)
  agg_f16_k<128, false><<<3125, 256, 0, stream>>>(xh, m1h, offs, deg, csr, nullptr, nullptr);
  gemm_f16_k<128, true, false, false><<<gg, 256, 0, stream>>>(
      m1h, ph_l1, pl_l1, xh, ph_r1, pl_r1, b1, h1h, nullptr, nullptr);

  // layer 2 (project-then-aggregate): [P|R] = h1 @ [Wl2;Wr2]^T; h2 = mean(P)+b2+R
  gemm_f16_k<128, false, true, false><<<gg, 256, 0, stream>>>(
      h1h, ph_c2, pl_c2, nullptr, nullptr, nullptr, nullptr, Ph, nullptr, Rh);
  agg_f16_k<64, true><<<1563, 256, 0, stream>>>(Ph, h2h, offs, deg, csr, b2, Rh);

  // layer 3 (aggregate-then-project): m3 = mean(h2); out = m3@Wl3^T + h2@Wr3^T + b3
  agg_f16_k<64, false><<<1563, 256, 0, stream>>>(h2h, m3h, offs, deg, csr, nullptr, nullptr);
  gemm_f16_k<64, true, false, true><<<gg, 256, 0, stream>>>(
      m3h, ph_l3, pl_l3, h2h, ph_r3, pl_r3, b3, nullptr, out, nullptr);
}